// Round 6
// baseline (179.808 us; speedup 1.0000x reference)
//
#include <hip/hip_runtime.h>
#include <hip/hip_bf16.h>

// B=8, NH=8, KS=VS=64, HW=1024, C=1536, GROUPS=24. pair = b*8+h (64 pairs).
// Pipeline: gn_partial -> pack (coalesced + LDS transpose, K/Q [s][c], V [c][s])
//           -> attn (S^T flash, 2-wave blocks, 2-way split-K, no online max).

typedef __attribute__((ext_vector_type(8))) short bf16x8;
typedef __attribute__((ext_vector_type(4))) float f32x4;
typedef unsigned short u16;
typedef unsigned int u32;

#define SM_SCALE 0.18033688f   // 0.125 * log2(e)
#define SM_OFF   8.0f          // fixed softmax offset (shift-invariant)

__device__ __forceinline__ u16 f2bf(float f) {   // RNE
    union { float f; u32 u; } a; a.f = f;
    return (u16)((a.u + 0x7fffu + ((a.u >> 16) & 1u)) >> 16);
}
__device__ __forceinline__ u32 pack2(float a, float b) {  // (bf(b)<<16)|bf(a)
    union { float f; u32 u; } ua, ub; ua.f = a; ub.f = b;
    return __builtin_amdgcn_perm(ub.u + 0x8000u, ua.u + 0x8000u, 0x07060302u);
}

// ---- Kernel 1: partial GN stats. 1536 blocks = 8 slices per (b,group).
__global__ __launch_bounds__(256) void gn_partial(const float* __restrict__ x,
                                                  float* __restrict__ partials) {
    int blk = blockIdx.x;
    const float4* p = (const float4*)(x + (size_t)blk * 8192);
    int t = threadIdx.x;
    float s1a = 0.f, s2a = 0.f, s1b = 0.f, s2b = 0.f;
#pragma unroll
    for (int i = 0; i < 8; i += 2) {
        float4 va = p[t + i * 256];
        float4 vb = p[t + (i + 1) * 256];
        s1a += va.x + va.y + va.z + va.w;
        s2a += va.x*va.x + va.y*va.y + va.z*va.z + va.w*va.w;
        s1b += vb.x + vb.y + vb.z + vb.w;
        s2b += vb.x*vb.x + vb.y*vb.y + vb.z*vb.z + vb.w*vb.w;
    }
    float s1 = s1a + s1b, s2 = s2a + s2b;
    for (int off = 32; off > 0; off >>= 1) {
        s1 += __shfl_down(s1, off);
        s2 += __shfl_down(s2, off);
    }
    __shared__ float a1[4], a2[4];
    int wave = t >> 6, lane = t & 63;
    if (lane == 0) { a1[wave] = s1; a2[wave] = s2; }
    __syncthreads();
    if (t == 0) {
        partials[blk * 2 + 0] = a1[0] + a1[1] + a1[2] + a1[3];
        partials[blk * 2 + 1] = a2[0] + a2[1] + a2[2] + a2[3];
    }
}

__device__ __forceinline__ void group_stats(const float* __restrict__ partials,
                                            int bg, float& mean, float& rstd) {
    float s1 = 0.f, s2 = 0.f;
#pragma unroll
    for (int j = 0; j < 8; ++j) {
        s1 += partials[(bg * 8 + j) * 2 + 0];
        s2 += partials[(bg * 8 + j) * 2 + 1];
    }
    mean = s1 * (1.f / 65536.f);
    float var = s2 * (1.f / 65536.f) - mean * mean;
    rstd = rsqrtf(var + 1e-5f);
}

// ---- Kernel 2: normalize + pack. COALESCED x loads (spatial on lanes);
// K,Q transposed to [s][c] via LDS; V [c][s] direct. Grid 1024 (st*64+pair).
__global__ __launch_bounds__(256) void pack_kernel(
    const float* __restrict__ x, const float* __restrict__ gamma,
    const float* __restrict__ beta, const float* __restrict__ partials,
    u16* __restrict__ Qn, u16* __restrict__ Kn, u16* __restrict__ Vn)
{
    const int st = blockIdx.x >> 6, pair = blockIdx.x & 63;
    const int b = pair >> 3, h = pair & 7;
    const float* xb = x + (size_t)b * 1536 * 1024;
    float ms[3], rs[3];
    group_stats(partials, b * 24 + 3 * h + 0, ms[0], rs[0]);
    group_stats(partials, b * 24 + 3 * h + 1, ms[1], rs[1]);
    group_stats(partials, b * 24 + 3 * h + 2, ms[2], rs[2]);

    const int t = threadIdx.x;
    __shared__ alignas(16) u16 Tsh[64][72];

    // K (t2=0) and Q (t2=1): load coalesced, transpose via LDS, store rows.
    for (int t2 = 0; t2 < 2; ++t2) {
        if (t2) __syncthreads();                 // Tsh reuse protection
        const int chl = t >> 4;                  // 0..15
        const int s4  = (t & 15) * 4;
#pragma unroll
        for (int dc = 0; dc < 4; ++dc) {
            int c = dc * 16 + chl;
            int cg = h * 192 + t2 * 64 + c;
            float4 v = *(const float4*)(xb + (size_t)cg * 1024 + st * 64 + s4);
            float wsc = gamma[cg] * rs[t2];
            float bsc = beta[cg] - ms[t2] * wsc;
            Tsh[s4 + 0][c] = f2bf(v.x * wsc + bsc);
            Tsh[s4 + 1][c] = f2bf(v.y * wsc + bsc);
            Tsh[s4 + 2][c] = f2bf(v.z * wsc + bsc);
            Tsh[s4 + 3][c] = f2bf(v.w * wsc + bsc);
        }
        __syncthreads();
        u16* dst = (t2 ? Qn : Kn) + (size_t)pair * 65536;
#pragma unroll
        for (int p = 0; p < 2; ++p) {
            int row = p * 32 + (t >> 3);
            int col = (t & 7) * 8;
            bf16x8 vv = *(const bf16x8*)&Tsh[row][col];
            *(bf16x8*)(dst + (size_t)(st * 64 + row) * 64 + col) = vv;
        }
    }
    // V: native [c][s], coalesced both sides.
    {
        const int s4 = (t & 15) * 4;
#pragma unroll
        for (int dc = 0; dc < 4; ++dc) {
            int c = dc * 16 + (t >> 4);
            int cg = h * 192 + 128 + c;
            float4 v = *(const float4*)(xb + (size_t)cg * 1024 + st * 64 + s4);
            float wsc = gamma[cg] * rs[2];
            float bsc = beta[cg] - ms[2] * wsc;
            uint2 o;
            o.x = pack2(v.x * wsc + bsc, v.y * wsc + bsc);
            o.y = pack2(v.z * wsc + bsc, v.w * wsc + bsc);
            *(uint2*)(Vn + (size_t)pair * 65536 + (size_t)c * 1024 + st * 64 + s4) = o;
        }
    }
}

// ---- Kernel 3: flash attention, S^T layout, no online max (fixed offset).
// Grid 2048: bid = qt*64 + pair (qt 0..31) -> bid%8 = pair%8 (XCD locality).
// Block = 128 thr = 2 waves: both waves own the same 32 queries; wave w does
// K-half w (split-K), merge O/l through LDS. 4096 waves = 16 waves/CU.
__global__ __launch_bounds__(128, 4) void attn_kernel(
    const u16* __restrict__ Qn, const u16* __restrict__ Kn,
    const u16* __restrict__ Vn, float* __restrict__ out)
{
    const int bid = blockIdx.x;
    const int qt = bid >> 6;        // 0..31
    const int pair = bid & 63;
    const int tid = threadIdx.x;
    const int w = tid >> 6;         // split-K half
    const int lane = tid & 63;
    const int grp = lane >> 4, li = lane & 15;

    __shared__ union {
        u16 pt[2][2][16][72];                            // [wave][qf][q=li][key]
        struct { float l[2][2][16]; float ot[2][16][72]; } mg;  // merge state
    } sm;

    const u16* Qp = Qn + (size_t)pair * 65536;
    const u16* Kp = Kn + (size_t)pair * 65536;
    const u16* Vp = Vn + (size_t)pair * 65536;

    // Q B-frags: B[n=q(li)][k=c = kh*32+grp*8+j]
    bf16x8 bq[2][2];
#pragma unroll
    for (int qf = 0; qf < 2; ++qf) {
        const u16* qrow = Qp + (size_t)(qt * 32 + qf * 16 + li) * 64 + grp * 8;
        bq[qf][0] = *(const bf16x8*)(qrow);
        bq[qf][1] = *(const bf16x8*)(qrow + 32);
    }

    f32x4 oacc[2][4];
#pragma unroll
    for (int qf = 0; qf < 2; ++qf)
#pragma unroll
        for (int vf = 0; vf < 4; ++vf) oacc[qf][vf] = f32x4{0.f, 0.f, 0.f, 0.f};
    float lsum[2] = {0.f, 0.f};

    const int kt0 = w * 8;
#pragma unroll 1
    for (int i = 0; i < 8; ++i) {
        const int kt = kt0 + i;
        // K A-frags: A[m=key][k=c]
        const u16* krow = Kp + (size_t)(kt * 64 + li) * 64 + grp * 8;
        bf16x8 ak[4][2];
#pragma unroll
        for (int kf = 0; kf < 4; ++kf) {
            ak[kf][0] = *(const bf16x8*)(krow + kf * 1024);
            ak[kf][1] = *(const bf16x8*)(krow + kf * 1024 + 32);
        }
        // S^T = K Q^T : rows=keys (kf*16+grp*4+r), cols=q (li)
        f32x4 sf[2][4];
#pragma unroll
        for (int qf = 0; qf < 2; ++qf)
#pragma unroll
            for (int kf = 0; kf < 4; ++kf) {
                f32x4 acc = f32x4{0.f, 0.f, 0.f, 0.f};
                acc = __builtin_amdgcn_mfma_f32_16x16x32_bf16(ak[kf][0], bq[qf][0], acc, 0, 0, 0);
                acc = __builtin_amdgcn_mfma_f32_16x16x32_bf16(ak[kf][1], bq[qf][1], acc, 0, 0, 0);
                sf[qf][kf] = acc;
            }
        // V A-frags (issued here to overlap with exp)
        const u16* vrow = Vp + (size_t)li * 1024 + kt * 64 + grp * 8;
        bf16x8 av[4][2];
#pragma unroll
        for (int vf = 0; vf < 4; ++vf) {
            av[vf][0] = *(const bf16x8*)(vrow + vf * 16384);
            av[vf][1] = *(const bf16x8*)(vrow + vf * 16384 + 32);
        }
        // P = exp2(s*scale - OFF): no max reduce, no rescale (shift-invariant)
#pragma unroll
        for (int qf = 0; qf < 2; ++qf)
#pragma unroll
            for (int kf = 0; kf < 4; ++kf) {
                float p0 = exp2f(__builtin_fmaf(sf[qf][kf][0], SM_SCALE, -SM_OFF));
                float p1 = exp2f(__builtin_fmaf(sf[qf][kf][1], SM_SCALE, -SM_OFF));
                float p2 = exp2f(__builtin_fmaf(sf[qf][kf][2], SM_SCALE, -SM_OFF));
                float p3 = exp2f(__builtin_fmaf(sf[qf][kf][3], SM_SCALE, -SM_OFF));
                lsum[qf] += (p0 + p1) + (p2 + p3);
                uint2 o; o.x = pack2(p0, p1); o.y = pack2(p2, p3);
                *(uint2*)&sm.pt[w][qf][li][kf * 16 + grp * 4] = o;
            }
        // O^T += V P : A=V (m=v, k=key), B=P (n=q=li, k=key)
#pragma unroll
        for (int qf = 0; qf < 2; ++qf)
#pragma unroll
            for (int kh = 0; kh < 2; ++kh) {
                bf16x8 bp = *(const bf16x8*)&sm.pt[w][qf][li][kh * 32 + grp * 8];
#pragma unroll
                for (int vf = 0; vf < 4; ++vf)
                    oacc[qf][vf] = __builtin_amdgcn_mfma_f32_16x16x32_bf16(av[vf][kh], bp, oacc[qf][vf], 0, 0, 0);
            }
    }

    // ---- finalize l across quads (deferred from the loop)
#pragma unroll
    for (int qf = 0; qf < 2; ++qf) {
        lsum[qf] += __shfl_xor(lsum[qf], 16);
        lsum[qf] += __shfl_xor(lsum[qf], 32);
    }

    // ---- split-K merge: wave w publishes oacc[w^1] + its l's; stores qf=w.
    __syncthreads();                 // all pt reads done before aliasing with mg
    if (grp == 0) { sm.mg.l[w][0][li] = lsum[0]; sm.mg.l[w][1][li] = lsum[1]; }
    {
        const int qo = w ^ 1;
#pragma unroll
        for (int vf = 0; vf < 4; ++vf)
            *(f32x4*)&sm.mg.ot[qo][li][vf * 16 + grp * 4] = oacc[qo][vf];
    }
    __syncthreads();
    float invl = 1.f / (lsum[w] + sm.mg.l[w ^ 1][w][li]);
    float* ob = out + (size_t)pair * 65536 + qt * 32 + w * 16 + li;
#pragma unroll
    for (int vf = 0; vf < 4; ++vf) {
        f32x4 other = *(const f32x4*)&sm.mg.ot[w][li][vf * 16 + grp * 4];
#pragma unroll
        for (int r = 0; r < 4; ++r) {
            int v = vf * 16 + grp * 4 + r;
            ob[(size_t)v * 1024] = (oacc[w][vf][r] + other[r]) * invl;
        }
    }
}

extern "C" void kernel_launch(void* const* d_in, const int* in_sizes, int n_in,
                              void* d_out, int out_size, void* d_ws, size_t ws_size,
                              hipStream_t stream) {
    const float* x     = (const float*)d_in[0];
    const float* gamma = (const float*)d_in[1];
    const float* beta  = (const float*)d_in[2];
    float* out = (float*)d_out;

    float* partials = (float*)d_ws;                       // 3072 f32
    u16* Qn = (u16*)((char*)d_ws + 32768);                // 8.4 MB
    u16* Kn = Qn + (size_t)64 * 65536;                    // 8.4 MB
    u16* Vn = Kn + (size_t)64 * 65536;                    // 8.4 MB (~25.2 MB total)

    gn_partial<<<1536, 256, 0, stream>>>(x, partials);
    pack_kernel<<<1024, 256, 0, stream>>>(x, gamma, beta, partials, Qn, Kn, Vn);
    attn_kernel<<<2048, 128, 0, stream>>>(Qn, Kn, Vn, out);
}